// Round 4
// baseline (6723.161 us; speedup 1.0000x reference)
//
#include <hip/hip_runtime.h>

// Workspace layout (floats), written by prep_kernel each call, then staged
// into LDS by every block of the main kernel. Weights feeding tanh are
// pre-scaled by K = 2*log2(e) so tanh(a) = 1 - 2/(1+exp2(a')) directly.
#define OFF_WIH 0      // 32   : W_ih[k]*K
#define OFF_C   32     // 32   : (b_ih[k]+b_hh[k])*K
#define OFF_WHH 64     // 1024 : transposed W_hh*K at [j*32 + k] = whh[k][j]*K
#define OFF_W1  1088   // 1536 : col-major W1 at [m*16 + o]
#define OFF_B1  2624   // 16
#define OFF_W2  2640   // 128  : col-major W2 at [k*8 + o]
#define OFF_B2  2768   // 8
#define OFF_W3  2776   // 8
#define OFF_B3  2784   // 1
#define WTOT    2785

#define E 2            // elements per thread (E=4 spilled: 256 VGPR + 3.7GB scratch)

typedef __fp16 h2f __attribute__((ext_vector_type(2)));

__global__ void prep_kernel(const float* __restrict__ wih, const float* __restrict__ whh,
                            const float* __restrict__ bih, const float* __restrict__ bhh,
                            const float* __restrict__ w1,  const float* __restrict__ b1,
                            const float* __restrict__ w2,  const float* __restrict__ b2,
                            const float* __restrict__ w3,  const float* __restrict__ b3,
                            float* __restrict__ ws)
{
    const float K = 2.8853900817779268f; // 2*log2(e)
    const int t = threadIdx.x;
    if (t < 32) {
        ws[OFF_WIH + t] = wih[t] * K;
        ws[OFF_C   + t] = (bih[t] + bhh[t]) * K;
    }
    for (int i = t; i < 1024; i += 256) {          // W_hh [32,32]: ws[j*32+k]=whh[k*32+j]*K
        int r = i >> 5, c = i & 31;
        ws[OFF_WHH + c * 32 + r] = whh[i] * K;
    }
    for (int i = t; i < 1536; i += 256) {          // W1 [16,96] -> col-major
        int o = i / 96, m = i - o * 96;
        ws[OFF_W1 + m * 16 + o] = w1[i];
    }
    if (t < 16) ws[OFF_B1 + t] = b1[t];
    for (int i = t; i < 128; i += 256) {           // W2 [8,16] -> col-major
        int o = i >> 4, k = i & 15;
        ws[OFF_W2 + k * 8 + o] = w2[i];
    }
    if (t < 8) { ws[OFF_B2 + t] = b2[t]; ws[OFF_W3 + t] = w3[t]; }
    if (t == 0) ws[OFF_B3] = b3[0];
}

// tanh(a) given ap = 2*log2(e)*a
__device__ __forceinline__ float tanh_fast(float ap) {
    float e = __builtin_amdgcn_exp2f(ap);
    return fmaf(-2.0f, __builtin_amdgcn_rcpf(e + 1.0f), 1.0f);
}

// One RNN timestep for E elements. hin/hout: packed-fp16 hidden state carrier.
// fc1 is accumulated immediately from the fp32 h (full precision on that path).
template<bool FIRST>
__device__ __forceinline__ void rnn_step(const float* __restrict__ W, int t,
                                         const float xt[E], const h2f hin[E][16],
                                         h2f hout[E][16], float f1[E][16])
{
    #pragma unroll
    for (int kt = 0; kt < 8; ++kt) {              // k-tiles of 4
        const int k0 = kt * 4;
        const float4 wih4 = *(const float4*)(W + OFF_WIH + k0);
        const float4 c4   = *(const float4*)(W + OFF_C   + k0);
        float acc[E][4];
        #pragma unroll
        for (int e = 0; e < E; ++e) {
            acc[e][0] = fmaf(xt[e], wih4.x, c4.x);
            acc[e][1] = fmaf(xt[e], wih4.y, c4.y);
            acc[e][2] = fmaf(xt[e], wih4.z, c4.z);
            acc[e][3] = fmaf(xt[e], wih4.w, c4.w);
        }
        if (!FIRST) {
            #pragma unroll
            for (int j = 0; j < 32; ++j) {
                const float4 w4 = *(const float4*)(W + OFF_WHH + j * 32 + k0);
                #pragma unroll
                for (int e = 0; e < E; ++e) {
                    const float hj = (float)hin[e][j >> 1][j & 1];
                    acc[e][0] = fmaf(hj, w4.x, acc[e][0]);
                    acc[e][1] = fmaf(hj, w4.y, acc[e][1]);
                    acc[e][2] = fmaf(hj, w4.z, acc[e][2]);
                    acc[e][3] = fmaf(hj, w4.w, acc[e][3]);
                }
            }
        }
        // tanh (in place) + pack carrier for next timestep
        #pragma unroll
        for (int e = 0; e < E; ++e) {
            #pragma unroll
            for (int kk = 0; kk < 4; ++kk) acc[e][kk] = tanh_fast(acc[e][kk]);
            hout[e][(k0 >> 1) + 0] = __builtin_amdgcn_cvt_pkrtz(acc[e][0], acc[e][1]);
            hout[e][(k0 >> 1) + 1] = __builtin_amdgcn_cvt_pkrtz(acc[e][2], acc[e][3]);
        }
        // fc1 accumulation from fp32 h
        #pragma unroll
        for (int kk = 0; kk < 4; ++kk) {
            const float* w1p = W + OFF_W1 + (t * 32 + k0 + kk) * 16;
            float w1r[16];
            *(float4*)(w1r + 0)  = *(const float4*)(w1p + 0);
            *(float4*)(w1r + 4)  = *(const float4*)(w1p + 4);
            *(float4*)(w1r + 8)  = *(const float4*)(w1p + 8);
            *(float4*)(w1r + 12) = *(const float4*)(w1p + 12);
            #pragma unroll
            for (int e = 0; e < E; ++e) {
                const float r = fmaxf(acc[e][kk], 0.0f);
                #pragma unroll
                for (int o = 0; o < 16; ++o)
                    f1[e][o] = fmaf(r, w1r[o], f1[e][o]);
            }
        }
    }
}

__global__ __launch_bounds__(256)
void rnn_mlp_kernel(const float* __restrict__ x, const float* __restrict__ ws,
                    float* __restrict__ out, int B)
{
    __shared__ __align__(16) float W[WTOT];
    for (int i = threadIdx.x; i < WTOT; i += 256) W[i] = ws[i];
    __syncthreads();

    const int tid = blockIdx.x * 256 + threadIdx.x;
    const int TOT = gridDim.x * 256;

    int es[E];
    bool val[E];
    #pragma unroll
    for (int e = 0; e < E; ++e) { es[e] = tid + e * TOT; val[e] = es[e] < B; }

    float f1[E][16];
    {
        float b1r[16];
        *(float4*)(b1r + 0)  = *(const float4*)(W + OFF_B1 + 0);
        *(float4*)(b1r + 4)  = *(const float4*)(W + OFF_B1 + 4);
        *(float4*)(b1r + 8)  = *(const float4*)(W + OFF_B1 + 8);
        *(float4*)(b1r + 12) = *(const float4*)(W + OFF_B1 + 12);
        #pragma unroll
        for (int e = 0; e < E; ++e)
            #pragma unroll
            for (int o = 0; o < 16; ++o) f1[e][o] = b1r[o];
    }

    h2f hA[E][16], hB[E][16];
    float xt[E];

    #pragma unroll
    for (int e = 0; e < E; ++e) xt[e] = val[e] ? x[3 * es[e] + 0] : 0.0f;
    rnn_step<true>(W, 0, xt, hA, hA, f1);

    #pragma unroll
    for (int e = 0; e < E; ++e) xt[e] = val[e] ? x[3 * es[e] + 1] : 0.0f;
    rnn_step<false>(W, 1, xt, hA, hB, f1);

    #pragma unroll
    for (int e = 0; e < E; ++e) xt[e] = val[e] ? x[3 * es[e] + 2] : 0.0f;
    rnn_step<false>(W, 2, xt, hB, hA, f1);   // hA write is dead -> DCE

    // fc2 (16 -> 8)
    float g[E][8];
    {
        float b2r[8];
        *(float4*)(b2r + 0) = *(const float4*)(W + OFF_B2 + 0);
        *(float4*)(b2r + 4) = *(const float4*)(W + OFF_B2 + 4);
        #pragma unroll
        for (int e = 0; e < E; ++e)
            #pragma unroll
            for (int o = 0; o < 8; ++o) g[e][o] = b2r[o];
    }
    #pragma unroll
    for (int k = 0; k < 16; ++k) {
        float w2r[8];
        *(float4*)(w2r + 0) = *(const float4*)(W + OFF_W2 + k * 8 + 0);
        *(float4*)(w2r + 4) = *(const float4*)(W + OFF_W2 + k * 8 + 4);
        #pragma unroll
        for (int e = 0; e < E; ++e) {
            const float v = f1[e][k];
            #pragma unroll
            for (int o = 0; o < 8; ++o)
                g[e][o] = fmaf(v, w2r[o], g[e][o]);
        }
    }

    // fc3 (8 -> 1)
    float w3r[8];
    *(float4*)(w3r + 0) = *(const float4*)(W + OFF_W3 + 0);
    *(float4*)(w3r + 4) = *(const float4*)(W + OFF_W3 + 4);
    const float b3 = W[OFF_B3];
    #pragma unroll
    for (int e = 0; e < E; ++e) {
        float y = b3;
        #pragma unroll
        for (int o = 0; o < 8; ++o)
            y = fmaf(fmaxf(g[e][o], 0.0f), w3r[o], y);
        if (val[e]) out[es[e]] = y;
    }
}

extern "C" void kernel_launch(void* const* d_in, const int* in_sizes, int n_in,
                              void* d_out, int out_size, void* d_ws, size_t ws_size,
                              hipStream_t stream)
{
    const float* x   = (const float*)d_in[0];
    const float* wih = (const float*)d_in[1];
    const float* whh = (const float*)d_in[2];
    const float* bih = (const float*)d_in[3];
    const float* bhh = (const float*)d_in[4];
    const float* w1  = (const float*)d_in[5];
    const float* b1  = (const float*)d_in[6];
    const float* w2  = (const float*)d_in[7];
    const float* b2  = (const float*)d_in[8];
    const float* w3  = (const float*)d_in[9];
    const float* b3  = (const float*)d_in[10];
    float* out = (float*)d_out;
    float* ws  = (float*)d_ws;

    const int B = in_sizes[0] / 3;
    const int nthreads = (B + E - 1) / E;
    const int grid = (nthreads + 255) / 256;

    prep_kernel<<<1, 256, 0, stream>>>(wih, whh, bih, bhh, w1, b1, w2, b2, w3, b3, ws);
    rnn_mlp_kernel<<<grid, 256, 0, stream>>>(x, ws, out, B);
}

// Round 5
// 2890.044 us; speedup vs baseline: 2.3263x; 2.3263x over previous
//
#include <hip/hip_runtime.h>

#define E 2   // elements per thread

// 32-bit-word offsets shared by workspace and LDS image.
// Packed-fp16 section first (uints), fp32 section after.
#define OFF_WHH2 0      // 512 : [jp*32+k] = pack(whh[k][2jp]*K, whh[k][2jp+1]*K)
#define OFF_W12  512    // 768 : [mp*16+o] = pack(w1[o][2mp], w1[o][2mp+1]), mp=0..47
#define OFF_WIH  1280   // 32  : fp32 wih[k]*K
#define OFF_C    1312   // 32  : fp32 (bih+bhh)[k]*K
#define OFF_B1   1344   // 16  : fp32
#define OFF_W2   1360   // 128 : fp32 col-major [k*8+o]
#define OFF_B2   1488   // 8
#define OFF_W3   1496   // 8
#define OFF_B3   1504   // 1
#define WTOT     1505

typedef __fp16 h2f __attribute__((ext_vector_type(2)));

union U32 { unsigned u; h2f h; float f; };

__device__ __forceinline__ h2f as_h2(unsigned u) { U32 x; x.u = u; return x.h; }

__device__ __forceinline__ unsigned pack2(float a, float b) {
    U32 x; x.h[0] = (__fp16)a; x.h[1] = (__fp16)b; return x.u;   // RNE casts
}

#if __has_builtin(__builtin_amdgcn_fdot2)
__device__ __forceinline__ float dot2(h2f a, h2f b, float c) {
    return __builtin_amdgcn_fdot2(a, b, c, false);
}
#else
__device__ __forceinline__ float dot2(h2f a, h2f b, float c) {
    return fmaf((float)a[0], (float)b[0], fmaf((float)a[1], (float)b[1], c));
}
#endif

// tanh(a) given ap = 2*log2(e)*a
__device__ __forceinline__ float tanh_fast(float ap) {
    float e = __builtin_amdgcn_exp2f(ap);
    return fmaf(-2.0f, __builtin_amdgcn_rcpf(e + 1.0f), 1.0f);
}

__global__ void prep_kernel(const float* __restrict__ wih, const float* __restrict__ whh,
                            const float* __restrict__ bih, const float* __restrict__ bhh,
                            const float* __restrict__ w1,  const float* __restrict__ b1,
                            const float* __restrict__ w2,  const float* __restrict__ b2,
                            const float* __restrict__ w3,  const float* __restrict__ b3,
                            unsigned* __restrict__ ws)
{
    const float K = 2.8853900817779268f; // 2*log2(e)
    const int t = threadIdx.x;
    for (int i = t; i < 512; i += 256) {           // W_hh packed pairs, transposed+scaled
        int jp = i >> 5, k = i & 31;
        ws[OFF_WHH2 + i] = pack2(whh[k * 32 + 2 * jp] * K, whh[k * 32 + 2 * jp + 1] * K);
    }
    for (int i = t; i < 768; i += 256) {           // W1 packed pairs, col-major over o
        int mp = i >> 4, o = i & 15;
        ws[OFF_W12 + i] = pack2(w1[o * 96 + 2 * mp], w1[o * 96 + 2 * mp + 1]);
    }
    float* wf = (float*)ws;
    if (t < 32) { wf[OFF_WIH + t] = wih[t] * K; wf[OFF_C + t] = (bih[t] + bhh[t]) * K; }
    if (t < 16) wf[OFF_B1 + t] = b1[t];
    if (t < 128) { int o = t >> 4, k = t & 15; wf[OFF_W2 + k * 8 + o] = w2[t]; }
    if (t < 8)  { wf[OFF_B2 + t] = b2[t]; wf[OFF_W3 + t] = w3[t]; }
    if (t == 0) wf[OFF_B3] = b3[0];
}

// One RNN timestep for E elements; hin/hout are packed-fp16 ping-pong buffers.
// fc1 is accumulated immediately (fp32 accumulators, dot2 of relu-pairs).
template<bool FIRST>
__device__ __forceinline__ void rnn_step(const unsigned* __restrict__ LW, const float* __restrict__ LF,
                                         const int t, const float xt[E],
                                         const h2f hin[E][16], h2f hout[E][16], float f1[E][16])
{
    #pragma unroll
    for (int kt = 0; kt < 8; ++kt) {              // k-tiles of 4
        const int k0 = kt * 4;
        float acc[E][4];
        #pragma unroll
        for (int e = 0; e < E; ++e) {
            #pragma unroll
            for (int kk = 0; kk < 4; ++kk)
                acc[e][kk] = fmaf(xt[e], LF[OFF_WIH + k0 + kk], LF[OFF_C + k0 + kk]);
        }
        if (!FIRST) {
            #pragma unroll
            for (int jp = 0; jp < 16; ++jp) {
                const uint4 w = *(const uint4*)(LW + OFF_WHH2 + jp * 32 + k0);
                #pragma unroll
                for (int e = 0; e < E; ++e) {
                    const h2f hp = hin[e][jp];
                    acc[e][0] = dot2(hp, as_h2(w.x), acc[e][0]);
                    acc[e][1] = dot2(hp, as_h2(w.y), acc[e][1]);
                    acc[e][2] = dot2(hp, as_h2(w.z), acc[e][2]);
                    acc[e][3] = dot2(hp, as_h2(w.w), acc[e][3]);
                }
            }
        }
        // tanh + pack carrier + relu pairs
        h2f r2[E][2];
        #pragma unroll
        for (int e = 0; e < E; ++e) {
            const float t0 = tanh_fast(acc[e][0]);
            const float t1 = tanh_fast(acc[e][1]);
            const float t2 = tanh_fast(acc[e][2]);
            const float t3 = tanh_fast(acc[e][3]);
            hout[e][kt * 2 + 0] = __builtin_amdgcn_cvt_pkrtz(t0, t1);
            hout[e][kt * 2 + 1] = __builtin_amdgcn_cvt_pkrtz(t2, t3);
            r2[e][0] = __builtin_amdgcn_cvt_pkrtz(fmaxf(t0, 0.0f), fmaxf(t1, 0.0f));
            r2[e][1] = __builtin_amdgcn_cvt_pkrtz(fmaxf(t2, 0.0f), fmaxf(t3, 0.0f));
        }
        // fc1 accumulation: 2 input-pairs per k-tile, 16 outputs each
        #pragma unroll
        for (int p = 0; p < 2; ++p) {
            const int mp = t * 16 + kt * 2 + p;
            const uint4 wa = *(const uint4*)(LW + OFF_W12 + mp * 16 + 0);
            const uint4 wb = *(const uint4*)(LW + OFF_W12 + mp * 16 + 4);
            const uint4 wc = *(const uint4*)(LW + OFF_W12 + mp * 16 + 8);
            const uint4 wd = *(const uint4*)(LW + OFF_W12 + mp * 16 + 12);
            #pragma unroll
            for (int e = 0; e < E; ++e) {
                const h2f r = r2[e][p];
                f1[e][0]  = dot2(r, as_h2(wa.x), f1[e][0]);
                f1[e][1]  = dot2(r, as_h2(wa.y), f1[e][1]);
                f1[e][2]  = dot2(r, as_h2(wa.z), f1[e][2]);
                f1[e][3]  = dot2(r, as_h2(wa.w), f1[e][3]);
                f1[e][4]  = dot2(r, as_h2(wb.x), f1[e][4]);
                f1[e][5]  = dot2(r, as_h2(wb.y), f1[e][5]);
                f1[e][6]  = dot2(r, as_h2(wb.z), f1[e][6]);
                f1[e][7]  = dot2(r, as_h2(wb.w), f1[e][7]);
                f1[e][8]  = dot2(r, as_h2(wc.x), f1[e][8]);
                f1[e][9]  = dot2(r, as_h2(wc.y), f1[e][9]);
                f1[e][10] = dot2(r, as_h2(wc.z), f1[e][10]);
                f1[e][11] = dot2(r, as_h2(wc.w), f1[e][11]);
                f1[e][12] = dot2(r, as_h2(wd.x), f1[e][12]);
                f1[e][13] = dot2(r, as_h2(wd.y), f1[e][13]);
                f1[e][14] = dot2(r, as_h2(wd.z), f1[e][14]);
                f1[e][15] = dot2(r, as_h2(wd.w), f1[e][15]);
            }
        }
    }
}

__global__ __launch_bounds__(256, 3)   // VGPR cap ~170: prevents the R3/R4 spill blowup
void rnn_mlp_kernel(const float* __restrict__ x, const unsigned* __restrict__ ws,
                    float* __restrict__ out, int B)
{
    __shared__ __align__(16) unsigned LW[WTOT + 3];
    for (int i = threadIdx.x; i < WTOT; i += 256) LW[i] = ws[i];
    __syncthreads();
    const float* LF = (const float*)LW;

    const int tid = blockIdx.x * 256 + threadIdx.x;
    const int TOT = gridDim.x * 256;

    int es[E]; bool val[E];
    #pragma unroll
    for (int e = 0; e < E; ++e) { es[e] = tid + e * TOT; val[e] = es[e] < B; }

    float f1[E][16];
    #pragma unroll
    for (int e = 0; e < E; ++e)
        #pragma unroll
        for (int o = 0; o < 16; ++o) f1[e][o] = LF[OFF_B1 + o];

    h2f hA[E][16], hB[E][16];
    float xt[E];

    #pragma unroll
    for (int e = 0; e < E; ++e) xt[e] = val[e] ? x[3 * es[e] + 0] : 0.0f;
    rnn_step<true>(LW, LF, 0, xt, hA, hA, f1);

    #pragma unroll
    for (int e = 0; e < E; ++e) xt[e] = val[e] ? x[3 * es[e] + 1] : 0.0f;
    rnn_step<false>(LW, LF, 1, xt, hA, hB, f1);

    #pragma unroll
    for (int e = 0; e < E; ++e) xt[e] = val[e] ? x[3 * es[e] + 2] : 0.0f;
    rnn_step<false>(LW, LF, 2, xt, hB, hA, f1);   // hA write is dead

    // fc2 (16 -> 8) fp32
    float g[E][8];
    #pragma unroll
    for (int e = 0; e < E; ++e)
        #pragma unroll
        for (int o = 0; o < 8; ++o) g[e][o] = LF[OFF_B2 + o];
    #pragma unroll
    for (int k = 0; k < 16; ++k) {
        const float4 wlo = *(const float4*)(LF + OFF_W2 + k * 8 + 0);
        const float4 whi = *(const float4*)(LF + OFF_W2 + k * 8 + 4);
        #pragma unroll
        for (int e = 0; e < E; ++e) {
            const float v = f1[e][k];
            g[e][0] = fmaf(v, wlo.x, g[e][0]);
            g[e][1] = fmaf(v, wlo.y, g[e][1]);
            g[e][2] = fmaf(v, wlo.z, g[e][2]);
            g[e][3] = fmaf(v, wlo.w, g[e][3]);
            g[e][4] = fmaf(v, whi.x, g[e][4]);
            g[e][5] = fmaf(v, whi.y, g[e][5]);
            g[e][6] = fmaf(v, whi.z, g[e][6]);
            g[e][7] = fmaf(v, whi.w, g[e][7]);
        }
    }

    // fc3 (8 -> 1)
    const float4 w3lo = *(const float4*)(LF + OFF_W3 + 0);
    const float4 w3hi = *(const float4*)(LF + OFF_W3 + 4);
    const float b3 = LF[OFF_B3];
    #pragma unroll
    for (int e = 0; e < E; ++e) {
        float y = b3;
        y = fmaf(fmaxf(g[e][0], 0.0f), w3lo.x, y);
        y = fmaf(fmaxf(g[e][1], 0.0f), w3lo.y, y);
        y = fmaf(fmaxf(g[e][2], 0.0f), w3lo.z, y);
        y = fmaf(fmaxf(g[e][3], 0.0f), w3lo.w, y);
        y = fmaf(fmaxf(g[e][4], 0.0f), w3hi.x, y);
        y = fmaf(fmaxf(g[e][5], 0.0f), w3hi.y, y);
        y = fmaf(fmaxf(g[e][6], 0.0f), w3hi.z, y);
        y = fmaf(fmaxf(g[e][7], 0.0f), w3hi.w, y);
        if (val[e]) out[es[e]] = y;
    }
}

extern "C" void kernel_launch(void* const* d_in, const int* in_sizes, int n_in,
                              void* d_out, int out_size, void* d_ws, size_t ws_size,
                              hipStream_t stream)
{
    const float* x   = (const float*)d_in[0];
    const float* wih = (const float*)d_in[1];
    const float* whh = (const float*)d_in[2];
    const float* bih = (const float*)d_in[3];
    const float* bhh = (const float*)d_in[4];
    const float* w1  = (const float*)d_in[5];
    const float* b1  = (const float*)d_in[6];
    const float* w2  = (const float*)d_in[7];
    const float* b2  = (const float*)d_in[8];
    const float* w3  = (const float*)d_in[9];
    const float* b3  = (const float*)d_in[10];
    float* out   = (float*)d_out;
    unsigned* ws = (unsigned*)d_ws;

    const int B = in_sizes[0] / 3;
    const int nthreads = (B + E - 1) / E;
    const int grid = (nthreads + 255) / 256;

    prep_kernel<<<1, 256, 0, stream>>>(wih, whh, bih, bhh, w1, b1, w2, b2, w3, b3, ws);
    rnn_mlp_kernel<<<grid, 256, 0, stream>>>(x, ws, out, B);
}

// Round 6
// 2878.494 us; speedup vs baseline: 2.3357x; 1.0040x over previous
//
#include <hip/hip_runtime.h>

#define E 2   // elements per thread

// 32-bit-word offsets shared by workspace and LDS image.
#define OFF_WHH2 0      // 512 : [jp*32+k] = pack(whh[k][2jp]*K, whh[k][2jp+1]*K)
#define OFF_W12  512    // 768 : [mp*16+o] = pack(w1[o][2mp], w1[o][2mp+1]), mp=0..47
#define OFF_WIH  1280   // 32  : fp32 wih[k]*K
#define OFF_C    1312   // 32  : fp32 (bih+bhh)[k]*K
#define OFF_B1   1344   // 16  : fp32
#define OFF_W2   1360   // 128 : fp32 col-major [k*8+o]
#define OFF_B2   1488   // 8
#define OFF_W3   1496   // 8
#define OFF_B3   1504   // 1
#define WTOT     1505

typedef __fp16 h2f __attribute__((ext_vector_type(2)));

union U32 { unsigned u; h2f h; float f; };

__device__ __forceinline__ h2f as_h2(unsigned u) { U32 x; x.u = u; return x.h; }

__device__ __forceinline__ unsigned pack2(float a, float b) {
    U32 x; x.h[0] = (__fp16)a; x.h[1] = (__fp16)b; return x.u;   // RNE casts
}

#if __has_builtin(__builtin_amdgcn_fdot2)
__device__ __forceinline__ float dot2(h2f a, h2f b, float c) {
    return __builtin_amdgcn_fdot2(a, b, c, false);
}
#else
__device__ __forceinline__ float dot2(h2f a, h2f b, float c) {
    return fmaf((float)a[0], (float)b[0], fmaf((float)a[1], (float)b[1], c));
}
#endif

// tanh(a) given ap = 2*log2(e)*a
__device__ __forceinline__ float tanh_fast(float ap) {
    float e = __builtin_amdgcn_exp2f(ap);
    return fmaf(-2.0f, __builtin_amdgcn_rcpf(e + 1.0f), 1.0f);
}

__global__ void prep_kernel(const float* __restrict__ wih, const float* __restrict__ whh,
                            const float* __restrict__ bih, const float* __restrict__ bhh,
                            const float* __restrict__ w1,  const float* __restrict__ b1,
                            const float* __restrict__ w2,  const float* __restrict__ b2,
                            const float* __restrict__ w3,  const float* __restrict__ b3,
                            unsigned* __restrict__ ws)
{
    const float K = 2.8853900817779268f; // 2*log2(e)
    const int t = threadIdx.x;
    for (int i = t; i < 512; i += 256) {           // W_hh packed pairs, transposed+scaled
        int jp = i >> 5, k = i & 31;
        ws[OFF_WHH2 + i] = pack2(whh[k * 32 + 2 * jp] * K, whh[k * 32 + 2 * jp + 1] * K);
    }
    for (int i = t; i < 768; i += 256) {           // W1 packed pairs, col-major over o
        int mp = i >> 4, o = i & 15;
        ws[OFF_W12 + i] = pack2(w1[o * 96 + 2 * mp], w1[o * 96 + 2 * mp + 1]);
    }
    float* wf = (float*)ws;
    if (t < 32) { wf[OFF_WIH + t] = wih[t] * K; wf[OFF_C + t] = (bih[t] + bhh[t]) * K; }
    if (t < 16) wf[OFF_B1 + t] = b1[t];
    if (t < 128) { int o = t >> 4, k = t & 15; wf[OFF_W2 + k * 8 + o] = w2[t]; }
    if (t < 8)  { wf[OFF_B2 + t] = b2[t]; wf[OFF_W3 + t] = w3[t]; }
    if (t == 0) wf[OFF_B3] = b3[0];
}

// One RNN timestep, textually expanded in the kernel body (no function
// boundary: array params into a helper defeated SROA in R3-R5 -> all state
// lived in scratch -> 8.9 GB HBM scratch traffic). All indices constant.
#define RNN_STEP(T, FIRST, HIN, HOUT)                                          \
    _Pragma("unroll")                                                          \
    for (int kt = 0; kt < 8; ++kt) {                                           \
        const int k0 = kt * 4;                                                 \
        float acc[E][4];                                                       \
        const float4 wih4 = *(const float4*)(LF + OFF_WIH + k0);               \
        const float4 c4   = *(const float4*)(LF + OFF_C   + k0);               \
        _Pragma("unroll")                                                      \
        for (int e = 0; e < E; ++e) {                                          \
            acc[e][0] = fmaf(xt[e], wih4.x, c4.x);                             \
            acc[e][1] = fmaf(xt[e], wih4.y, c4.y);                             \
            acc[e][2] = fmaf(xt[e], wih4.z, c4.z);                             \
            acc[e][3] = fmaf(xt[e], wih4.w, c4.w);                             \
        }                                                                      \
        if (!(FIRST)) {                                                        \
            _Pragma("unroll")                                                  \
            for (int jp = 0; jp < 16; ++jp) {                                  \
                const uint4 w = *(const uint4*)(LW + OFF_WHH2 + jp * 32 + k0); \
                _Pragma("unroll")                                              \
                for (int e = 0; e < E; ++e) {                                  \
                    const h2f hp = HIN[e][jp];                                 \
                    acc[e][0] = dot2(hp, as_h2(w.x), acc[e][0]);               \
                    acc[e][1] = dot2(hp, as_h2(w.y), acc[e][1]);               \
                    acc[e][2] = dot2(hp, as_h2(w.z), acc[e][2]);               \
                    acc[e][3] = dot2(hp, as_h2(w.w), acc[e][3]);               \
                }                                                              \
            }                                                                  \
        }                                                                      \
        h2f r2[E][2];                                                          \
        _Pragma("unroll")                                                      \
        for (int e = 0; e < E; ++e) {                                          \
            const float t0 = tanh_fast(acc[e][0]);                             \
            const float t1 = tanh_fast(acc[e][1]);                             \
            const float t2 = tanh_fast(acc[e][2]);                             \
            const float t3 = tanh_fast(acc[e][3]);                             \
            HOUT[e][kt * 2 + 0] = __builtin_amdgcn_cvt_pkrtz(t0, t1);          \
            HOUT[e][kt * 2 + 1] = __builtin_amdgcn_cvt_pkrtz(t2, t3);          \
            r2[e][0] = __builtin_amdgcn_cvt_pkrtz(fmaxf(t0, 0.0f), fmaxf(t1, 0.0f)); \
            r2[e][1] = __builtin_amdgcn_cvt_pkrtz(fmaxf(t2, 0.0f), fmaxf(t3, 0.0f)); \
        }                                                                      \
        _Pragma("unroll")                                                      \
        for (int p = 0; p < 2; ++p) {                                          \
            const int mp = (T) * 16 + kt * 2 + p;                              \
            const uint4 wa = *(const uint4*)(LW + OFF_W12 + mp * 16 + 0);      \
            const uint4 wb = *(const uint4*)(LW + OFF_W12 + mp * 16 + 4);      \
            const uint4 wc = *(const uint4*)(LW + OFF_W12 + mp * 16 + 8);      \
            const uint4 wd = *(const uint4*)(LW + OFF_W12 + mp * 16 + 12);     \
            _Pragma("unroll")                                                  \
            for (int e = 0; e < E; ++e) {                                      \
                const h2f r = r2[e][p];                                        \
                f1[e][0]  = dot2(r, as_h2(wa.x), f1[e][0]);                    \
                f1[e][1]  = dot2(r, as_h2(wa.y), f1[e][1]);                    \
                f1[e][2]  = dot2(r, as_h2(wa.z), f1[e][2]);                    \
                f1[e][3]  = dot2(r, as_h2(wa.w), f1[e][3]);                    \
                f1[e][4]  = dot2(r, as_h2(wb.x), f1[e][4]);                    \
                f1[e][5]  = dot2(r, as_h2(wb.y), f1[e][5]);                    \
                f1[e][6]  = dot2(r, as_h2(wb.z), f1[e][6]);                    \
                f1[e][7]  = dot2(r, as_h2(wb.w), f1[e][7]);                    \
                f1[e][8]  = dot2(r, as_h2(wc.x), f1[e][8]);                    \
                f1[e][9]  = dot2(r, as_h2(wc.y), f1[e][9]);                    \
                f1[e][10] = dot2(r, as_h2(wc.z), f1[e][10]);                   \
                f1[e][11] = dot2(r, as_h2(wc.w), f1[e][11]);                   \
                f1[e][12] = dot2(r, as_h2(wd.x), f1[e][12]);                   \
                f1[e][13] = dot2(r, as_h2(wd.y), f1[e][13]);                   \
                f1[e][14] = dot2(r, as_h2(wd.z), f1[e][14]);                   \
                f1[e][15] = dot2(r, as_h2(wd.w), f1[e][15]);                   \
            }                                                                  \
        }                                                                      \
    }

__global__ __launch_bounds__(256, 3)   // VGPR cap ~170: stops scheduler-hoist blowup
void rnn_mlp_kernel(const float* __restrict__ x, const unsigned* __restrict__ ws,
                    float* __restrict__ out, int B)
{
    __shared__ __align__(16) unsigned LW[WTOT + 3];
    for (int i = threadIdx.x; i < WTOT; i += 256) LW[i] = ws[i];
    __syncthreads();
    const float* LF = (const float*)LW;

    const int tid = blockIdx.x * 256 + threadIdx.x;
    const int TOT = gridDim.x * 256;

    int es[E]; bool val[E];
    #pragma unroll
    for (int e = 0; e < E; ++e) { es[e] = tid + e * TOT; val[e] = es[e] < B; }

    float f1[E][16];
    #pragma unroll
    for (int e = 0; e < E; ++e)
        #pragma unroll
        for (int o = 0; o < 16; ++o) f1[e][o] = LF[OFF_B1 + o];

    h2f hA[E][16], hB[E][16];
    float xt[E];

    #pragma unroll
    for (int e = 0; e < E; ++e) xt[e] = val[e] ? x[3 * es[e] + 0] : 0.0f;
    RNN_STEP(0, 1, hA, hA)

    #pragma unroll
    for (int e = 0; e < E; ++e) xt[e] = val[e] ? x[3 * es[e] + 1] : 0.0f;
    RNN_STEP(1, 0, hA, hB)

    #pragma unroll
    for (int e = 0; e < E; ++e) xt[e] = val[e] ? x[3 * es[e] + 2] : 0.0f;
    RNN_STEP(2, 0, hB, hA)   // hA write is dead -> DCE

    // fc2 (16 -> 8) fp32
    float g[E][8];
    #pragma unroll
    for (int e = 0; e < E; ++e)
        #pragma unroll
        for (int o = 0; o < 8; ++o) g[e][o] = LF[OFF_B2 + o];
    #pragma unroll
    for (int k = 0; k < 16; ++k) {
        const float4 wlo = *(const float4*)(LF + OFF_W2 + k * 8 + 0);
        const float4 whi = *(const float4*)(LF + OFF_W2 + k * 8 + 4);
        #pragma unroll
        for (int e = 0; e < E; ++e) {
            const float v = f1[e][k];
            g[e][0] = fmaf(v, wlo.x, g[e][0]);
            g[e][1] = fmaf(v, wlo.y, g[e][1]);
            g[e][2] = fmaf(v, wlo.z, g[e][2]);
            g[e][3] = fmaf(v, wlo.w, g[e][3]);
            g[e][4] = fmaf(v, whi.x, g[e][4]);
            g[e][5] = fmaf(v, whi.y, g[e][5]);
            g[e][6] = fmaf(v, whi.z, g[e][6]);
            g[e][7] = fmaf(v, whi.w, g[e][7]);
        }
    }

    // fc3 (8 -> 1)
    const float4 w3lo = *(const float4*)(LF + OFF_W3 + 0);
    const float4 w3hi = *(const float4*)(LF + OFF_W3 + 4);
    const float b3 = LF[OFF_B3];
    #pragma unroll
    for (int e = 0; e < E; ++e) {
        float y = b3;
        y = fmaf(fmaxf(g[e][0], 0.0f), w3lo.x, y);
        y = fmaf(fmaxf(g[e][1], 0.0f), w3lo.y, y);
        y = fmaf(fmaxf(g[e][2], 0.0f), w3lo.z, y);
        y = fmaf(fmaxf(g[e][3], 0.0f), w3lo.w, y);
        y = fmaf(fmaxf(g[e][4], 0.0f), w3hi.x, y);
        y = fmaf(fmaxf(g[e][5], 0.0f), w3hi.y, y);
        y = fmaf(fmaxf(g[e][6], 0.0f), w3hi.z, y);
        y = fmaf(fmaxf(g[e][7], 0.0f), w3hi.w, y);
        if (val[e]) out[es[e]] = y;
    }
}

extern "C" void kernel_launch(void* const* d_in, const int* in_sizes, int n_in,
                              void* d_out, int out_size, void* d_ws, size_t ws_size,
                              hipStream_t stream)
{
    const float* x   = (const float*)d_in[0];
    const float* wih = (const float*)d_in[1];
    const float* whh = (const float*)d_in[2];
    const float* bih = (const float*)d_in[3];
    const float* bhh = (const float*)d_in[4];
    const float* w1  = (const float*)d_in[5];
    const float* b1  = (const float*)d_in[6];
    const float* w2  = (const float*)d_in[7];
    const float* b2  = (const float*)d_in[8];
    const float* w3  = (const float*)d_in[9];
    const float* b3  = (const float*)d_in[10];
    float* out   = (float*)d_out;
    unsigned* ws = (unsigned*)d_ws;

    const int B = in_sizes[0] / 3;
    const int nthreads = (B + E - 1) / E;
    const int grid = (nthreads + 255) / 256;

    prep_kernel<<<1, 256, 0, stream>>>(wih, whh, bih, bhh, w1, b1, w2, b2, w3, b3, ws);
    rnn_mlp_kernel<<<grid, 256, 0, stream>>>(x, ws, out, B);
}